// Round 2
// baseline (344.947 us; speedup 1.0000x reference)
//
#include <hip/hip_runtime.h>
#include <hip/hip_bf16.h>

typedef __bf16 bf16_t;
typedef __attribute__((ext_vector_type(8))) __bf16 bf16x8;
typedef __attribute__((ext_vector_type(4))) float f32x4;

#define DIM 2048
#define LAT 32
#define EPSF 1e-6f

__device__ __forceinline__ float gelu_f(float x) {
    return 0.5f * x * (1.0f + erff(x * 0.7071067811865475f));
}

// Pack We1 (2048x32 f32) and Wd2 (32x2048 f32) into bf16 MFMA B-fragment layout.
// B-frag for mfma_f32_16x16x32_bf16: lane l needs B[k = kgrp*8 + i][n = ntile*16 + (l&15)],
// kgrp = l>>4, i = 0..7, stored contiguously (16B per lane).
// (A-frag has the mirror layout, so Wd2p also serves as the A-operand of the
//  swapped/transposed decode MFMA.)
__global__ void pack_weights(const float* __restrict__ We1,
                             const float* __restrict__ Wd2,
                             bf16_t* __restrict__ We1p,
                             bf16_t* __restrict__ Wd2p) {
    int tid = blockIdx.x * 256 + threadIdx.x;  // 0..16383
    if (tid < 8192) {
        int l  = tid & 63;
        int nt = (tid >> 6) & 1;
        int t  = tid >> 7;
        int kg = l >> 4, mm = l & 15;
        int k0 = t * 32 + kg * 8;
        int n  = nt * 16 + mm;
        bf16_t* dst = We1p + (size_t)tid * 8;
#pragma unroll
        for (int i = 0; i < 8; ++i)
            dst[i] = (bf16_t)We1[(size_t)(k0 + i) * LAT + n];
    } else {
        int id = tid - 8192;
        int l  = id & 63;
        int nt = id >> 6;
        int kg = l >> 4, mm = l & 15;
        int n  = nt * 16 + mm;
        bf16_t* dst = Wd2p + (size_t)id * 8;
#pragma unroll
        for (int i = 0; i < 8; ++i)
            dst[i] = (bf16_t)Wd2[(size_t)(kg * 8 + i) * DIM + n];
    }
}

// 4 waves / block, 32 rows / block. Phase-1 wave roles: src = wave>>1 (z0/z1),
// rt = wave&1 (16-row tile). Phase-3 roles: rt = wave&1, nhalf = wave>>1.
__global__ __launch_bounds__(256, 4)
void fused_manifold(const float* __restrict__ z0, const float* __restrict__ z1,
                    const float* __restrict__ tp,
                    const bf16x8* __restrict__ We1p,
                    const float* __restrict__ be1,
                    const float* __restrict__ We2,
                    const float* __restrict__ be2,
                    const float* __restrict__ Wd1,
                    const float* __restrict__ bd1,
                    const bf16x8* __restrict__ Wd2p,
                    const float* __restrict__ bd2,
                    float* __restrict__ out) {
    const int tid  = threadIdx.x;
    const int wave = tid >> 6;
    const int lane = tid & 63;
    const int m16  = lane & 15;
    const int kg   = lane >> 4;
    const int src  = wave >> 1;   // phase 1: which z source
    const int rt   = wave & 1;    // row tile within block (0/1)
    const int blockRow = blockIdx.x * 32;

    __shared__ float We2s[LAT * 33];
    __shared__ float Wd1s[LAT * 33];
    __shared__ float s[2][2][16][LAT + 1];   // [src][rt][row][col]
    __shared__ float hm[2][16][LAT + 1];     // [rt][row][col]

    for (int i = tid; i < LAT * LAT; i += 256) {
        int r = i >> 5, c = i & 31;
        We2s[r * 33 + c] = We2[i];
        Wd1s[r * 33 + c] = Wd1[i];
    }

    // ---- Phase 1: S[src][rt] = z_src rows -> @ We1  (16 rows, N=32, K=2048)
    f32x4 acc0 = {0.f, 0.f, 0.f, 0.f};
    f32x4 acc1 = acc0;
    const float* zsrc = (src == 0) ? z0 : z1;
    const float* zp = zsrc + (size_t)(blockRow + rt * 16 + m16) * DIM + kg * 8;

#pragma unroll 2
    for (int t = 0; t < 64; ++t) {
        f32x4 alo = *(const f32x4*)(zp + t * 32);
        f32x4 ahi = *(const f32x4*)(zp + t * 32 + 4);
        bf16x8 b0 = We1p[(t * 2 + 0) * 64 + lane];
        bf16x8 b1 = We1p[(t * 2 + 1) * 64 + lane];
        bf16x8 a;
#pragma unroll
        for (int i = 0; i < 4; ++i) {
            a[i]     = (bf16_t)alo[i];
            a[i + 4] = (bf16_t)ahi[i];
        }
        acc0 = __builtin_amdgcn_mfma_f32_16x16x32_bf16(a, b0, acc0, 0, 0, 0);
        acc1 = __builtin_amdgcn_mfma_f32_16x16x32_bf16(a, b1, acc1, 0, 0, 0);
    }

    {
        float be1a = be1[m16], be1b = be1[16 + m16];
#pragma unroll
        for (int i = 0; i < 4; ++i) {
            int m = kg * 4 + i;
            s[src][rt][m][m16]      = gelu_f(acc0[i] + be1a);
            s[src][rt][m][16 + m16] = gelu_f(acc1[i] + be1b);
        }
    }
    __syncthreads();

    // ---- Phase 2 (waves 0,1): encode-2 + slerp for rows of tile `wave`
    if (wave < 2) {
        const int prt = wave;
        const int jb  = kg * 8;
        const float tval = tp[0];
        float h0v[8], h1v[8];
#pragma unroll
        for (int j = 0; j < 8; ++j) { h0v[j] = be2[jb + j]; h1v[j] = h0v[j]; }
        for (int k = 0; k < 32; ++k) {
            float a0k = s[0][prt][m16][k];
            float a1k = s[1][prt][m16][k];
#pragma unroll
            for (int j = 0; j < 8; ++j) {
                float w = We2s[k * 33 + jb + j];
                h0v[j] += a0k * w;
                h1v[j] += a1k * w;
            }
        }
        float ss0 = 0.f, ss1 = 0.f;
#pragma unroll
        for (int j = 0; j < 8; ++j) { ss0 += h0v[j] * h0v[j]; ss1 += h1v[j] * h1v[j]; }
        ss0 += __shfl_xor(ss0, 16); ss0 += __shfl_xor(ss0, 32);
        ss1 += __shfl_xor(ss1, 16); ss1 += __shfl_xor(ss1, 32);
        float n0 = sqrtf(ss0), n1 = sqrtf(ss1);
        float inv0 = 1.f / (n0 + EPSF), inv1 = 1.f / (n1 + EPSF);
        float dotp = 0.f;
#pragma unroll
        for (int j = 0; j < 8; ++j) dotp += (h0v[j] * inv0) * (h1v[j] * inv1);
        dotp += __shfl_xor(dotp, 16); dotp += __shfl_xor(dotp, 32);
        dotp = fminf(fmaxf(dotp, -1.f + EPSF), 1.f - EPSF);
        float theta   = acosf(dotp);
        float scale   = 0.5f * (n0 + n1);
        float inv_sin = 1.f / sinf(theta);
        // theta >= acos(1-1e-6) ~ 1.4e-3 > EPS: slerp branch always taken
        float c0 = sinf((1.f - tval) * theta) * inv_sin * scale * inv0;
        float c1 = sinf(tval * theta) * inv_sin * scale * inv1;
#pragma unroll
        for (int j = 0; j < 8; ++j)
            hm[prt][m16][jb + j] = c0 * h0v[j] + c1 * h1v[j];
    }
    __syncthreads();

    // ---- decode layer 1 (all waves; pairs duplicate per rt): g in A/B-frag layout
    bf16x8 afrag;
    {
        const int jb = kg * 8;
        float gv[8];
#pragma unroll
        for (int j = 0; j < 8; ++j) gv[j] = bd1[jb + j];
        for (int k = 0; k < 32; ++k) {
            float hk = hm[rt][m16][k];
#pragma unroll
            for (int j = 0; j < 8; ++j)
                gv[j] += hk * Wd1s[k * 33 + jb + j];
        }
#pragma unroll
        for (int j = 0; j < 8; ++j) afrag[j] = (bf16_t)gelu_f(gv[j]);
    }

    // ---- Phase 3: out_tile^T = Wd2tile^T @ g^T via swapped operands.
    // D lane layout becomes: row = m16 (out row), cols = ntile*16 + kg*4 + i
    // -> one contiguous dwordx4 store per lane.
    const int nhalf = wave >> 1;
    float* orow = out + (size_t)(blockRow + rt * 16 + m16) * DIM;
    for (int nt = 0; nt < 64; ++nt) {
        int ntile = nhalf * 64 + nt;
        bf16x8 bfrag = Wd2p[ntile * 64 + lane];
        f32x4 c = {0.f, 0.f, 0.f, 0.f};
        c = __builtin_amdgcn_mfma_f32_16x16x32_bf16(bfrag, afrag, c, 0, 0, 0);
        f32x4 bv = *(const f32x4*)(bd2 + ntile * 16 + kg * 4);
        f32x4 o;
#pragma unroll
        for (int i = 0; i < 4; ++i) o[i] = c[i] + bv[i];
        *(f32x4*)(orow + ntile * 16 + kg * 4) = o;
    }
}

extern "C" void kernel_launch(void* const* d_in, const int* in_sizes, int n_in,
                              void* d_out, int out_size, void* d_ws, size_t ws_size,
                              hipStream_t stream) {
    const float* z0  = (const float*)d_in[0];
    const float* z1  = (const float*)d_in[1];
    const float* tp  = (const float*)d_in[2];
    const float* We1 = (const float*)d_in[3];
    const float* be1 = (const float*)d_in[4];
    const float* We2 = (const float*)d_in[5];
    const float* be2 = (const float*)d_in[6];
    const float* Wd1 = (const float*)d_in[7];
    const float* bd1 = (const float*)d_in[8];
    const float* Wd2 = (const float*)d_in[9];
    const float* bd2 = (const float*)d_in[10];
    float* out = (float*)d_out;

    bf16_t* We1p = (bf16_t*)d_ws;                         // 65536 bf16 = 128 KB
    bf16_t* Wd2p = (bf16_t*)((char*)d_ws + 65536 * 2);    // 65536 bf16 = 128 KB

    hipLaunchKernelGGL(pack_weights, dim3(64), dim3(256), 0, stream,
                       We1, Wd2, We1p, Wd2p);
    hipLaunchKernelGGL(fused_manifold, dim3(1024), dim3(256), 0, stream,
                       z0, z1, tp, (const bf16x8*)We1p, be1, We2, be2,
                       Wd1, bd1, (const bf16x8*)Wd2p, bd2, out);
}

// Round 3
// 326.675 us; speedup vs baseline: 1.0559x; 1.0559x over previous
//
#include <hip/hip_runtime.h>
#include <hip/hip_bf16.h>

typedef __bf16 bf16_t;
typedef __attribute__((ext_vector_type(8))) __bf16 bf16x8;
typedef __attribute__((ext_vector_type(4))) float f32x4;

#define DIM 2048
#define LAT 32
#define EPSF 1e-6f

__device__ __forceinline__ float gelu_f(float x) {
    return 0.5f * x * (1.0f + erff(x * 0.7071067811865475f));
}

// Pack We1 (2048x32 f32) and Wd2 (32x2048 f32) into bf16 MFMA B-fragment layout.
// B-frag for mfma_f32_16x16x32_bf16: lane l needs B[k = kgrp*8 + i][n = ntile*16 + (l&15)],
// kgrp = l>>4, i = 0..7, stored contiguously (16B per lane).
__global__ void pack_weights(const float* __restrict__ We1,
                             const float* __restrict__ Wd2,
                             bf16_t* __restrict__ We1p,
                             bf16_t* __restrict__ Wd2p) {
    int tid = blockIdx.x * 256 + threadIdx.x;  // 0..16383
    if (tid < 8192) {
        int l  = tid & 63;
        int nt = (tid >> 6) & 1;
        int t  = tid >> 7;
        int kg = l >> 4, mm = l & 15;
        int k0 = t * 32 + kg * 8;
        int n  = nt * 16 + mm;
        bf16_t* dst = We1p + (size_t)tid * 8;
#pragma unroll
        for (int i = 0; i < 8; ++i)
            dst[i] = (bf16_t)We1[(size_t)(k0 + i) * LAT + n];
    } else {
        int id = tid - 8192;
        int l  = id & 63;
        int nt = id >> 6;
        int kg = l >> 4, mm = l & 15;
        int n  = nt * 16 + mm;
        bf16_t* dst = Wd2p + (size_t)id * 8;
#pragma unroll
        for (int i = 0; i < 8; ++i)
            dst[i] = (bf16_t)Wd2[(size_t)(kg * 8 + i) * DIM + n];
    }
}

// 512 threads = 8 waves per block; 64 rows per block (4 tiles of 16),
// grid = 512 blocks (identical row->block mapping and global access
// patterns to the R0 kernel). Wave wid: tile = wid>>1, kh = wid&1
// (K-half split of the encode GEMM; partial-sum reduce through LDS).
__global__ __launch_bounds__(512, 4)
void fused_manifold(const float* __restrict__ z0, const float* __restrict__ z1,
                    const float* __restrict__ tp,
                    const bf16x8* __restrict__ We1p,
                    const float* __restrict__ be1,
                    const float* __restrict__ We2,
                    const float* __restrict__ be2,
                    const float* __restrict__ Wd1,
                    const float* __restrict__ bd1,
                    const bf16x8* __restrict__ Wd2p,
                    const float* __restrict__ bd2,
                    float* __restrict__ out) {
    const int tid  = threadIdx.x;
    const int wid  = tid >> 6;
    const int lane = tid & 63;
    const int m16  = lane & 15;
    const int kg   = lane >> 4;
    const int tile = wid >> 1;   // 0..3 : which 16-row tile
    const int kh   = wid & 1;    // 0..1 : which K-half (encode GEMM)
    const int blockRow = blockIdx.x * 64;
    const int tileRow  = blockRow + tile * 16;

    __shared__ float We2s[LAT * 33];
    __shared__ float Wd1s[LAT * 33];
    __shared__ float s[2][64][LAT + 1];       // [src][row in block][col]
    __shared__ float partial[16][64][4];      // kh=1 partial sums: [tile*4+src*2+nt][lane][4]
    __shared__ float hm[64][LAT + 1];

    for (int i = tid; i < LAT * LAT; i += 512) {
        int r = i >> 5, c = i & 31;
        We2s[r * 33 + c] = We2[i];
        Wd1s[r * 33 + c] = Wd1[i];
    }

    // ---- Phase 1: half-K encode GEMM for this wave's tile, both sources.
    // acc[src][nt] ; K range = kh*1024 + t*32, t = 0..31
    f32x4 acc00 = {0.f, 0.f, 0.f, 0.f};
    f32x4 acc01 = acc00, acc10 = acc00, acc11 = acc00;
    const float* z0p = z0 + (size_t)(tileRow + m16) * DIM + kh * 1024 + kg * 8;
    const float* z1p = z1 + (size_t)(tileRow + m16) * DIM + kh * 1024 + kg * 8;
    const bf16x8* wp = We1p + (size_t)(kh * 64) * 64 + lane;

#pragma unroll 4
    for (int t = 0; t < 32; ++t) {
        f32x4 a0lo = *(const f32x4*)(z0p + t * 32);
        f32x4 a0hi = *(const f32x4*)(z0p + t * 32 + 4);
        f32x4 a1lo = *(const f32x4*)(z1p + t * 32);
        f32x4 a1hi = *(const f32x4*)(z1p + t * 32 + 4);
        bf16x8 b0 = wp[(t * 2 + 0) * 64];
        bf16x8 b1 = wp[(t * 2 + 1) * 64];
        bf16x8 a0, a1;
#pragma unroll
        for (int i = 0; i < 4; ++i) {
            a0[i]     = (bf16_t)a0lo[i];
            a0[i + 4] = (bf16_t)a0hi[i];
            a1[i]     = (bf16_t)a1lo[i];
            a1[i + 4] = (bf16_t)a1hi[i];
        }
        acc00 = __builtin_amdgcn_mfma_f32_16x16x32_bf16(a0, b0, acc00, 0, 0, 0);
        acc01 = __builtin_amdgcn_mfma_f32_16x16x32_bf16(a0, b1, acc01, 0, 0, 0);
        acc10 = __builtin_amdgcn_mfma_f32_16x16x32_bf16(a1, b0, acc10, 0, 0, 0);
        acc11 = __builtin_amdgcn_mfma_f32_16x16x32_bf16(a1, b1, acc11, 0, 0, 0);
    }

    // ---- K-half reduce through LDS: odd waves publish, even waves combine.
    if (kh == 1) {
        *(f32x4*)partial[tile * 4 + 0][lane] = acc00;
        *(f32x4*)partial[tile * 4 + 1][lane] = acc01;
        *(f32x4*)partial[tile * 4 + 2][lane] = acc10;
        *(f32x4*)partial[tile * 4 + 3][lane] = acc11;
    }
    __syncthreads();
    if (kh == 0) {
        f32x4 p00 = *(const f32x4*)partial[tile * 4 + 0][lane];
        f32x4 p01 = *(const f32x4*)partial[tile * 4 + 1][lane];
        f32x4 p10 = *(const f32x4*)partial[tile * 4 + 2][lane];
        f32x4 p11 = *(const f32x4*)partial[tile * 4 + 3][lane];
        float be1a = be1[m16], be1b = be1[16 + m16];
#pragma unroll
        for (int i = 0; i < 4; ++i) {
            int m = tile * 16 + kg * 4 + i;
            s[0][m][m16]      = gelu_f(acc00[i] + p00[i] + be1a);
            s[0][m][16 + m16] = gelu_f(acc01[i] + p01[i] + be1b);
            s[1][m][m16]      = gelu_f(acc10[i] + p10[i] + be1a);
            s[1][m][16 + m16] = gelu_f(acc11[i] + p11[i] + be1b);
        }
    }
    __syncthreads();

    // ---- Phase 2 (waves 0..3): encode-2 + slerp for tile ptile = wid
    if (wid < 4) {
        const int ptile = wid;
        const int row   = ptile * 16 + m16;
        const int jb    = kg * 8;
        const float tval = tp[0];
        float h0v[8], h1v[8];
#pragma unroll
        for (int j = 0; j < 8; ++j) { h0v[j] = be2[jb + j]; h1v[j] = h0v[j]; }
        for (int k = 0; k < 32; ++k) {
            float a0k = s[0][row][k];
            float a1k = s[1][row][k];
#pragma unroll
            for (int j = 0; j < 8; ++j) {
                float w = We2s[k * 33 + jb + j];
                h0v[j] += a0k * w;
                h1v[j] += a1k * w;
            }
        }
        float ss0 = 0.f, ss1 = 0.f;
#pragma unroll
        for (int j = 0; j < 8; ++j) { ss0 += h0v[j] * h0v[j]; ss1 += h1v[j] * h1v[j]; }
        ss0 += __shfl_xor(ss0, 16); ss0 += __shfl_xor(ss0, 32);
        ss1 += __shfl_xor(ss1, 16); ss1 += __shfl_xor(ss1, 32);
        float n0 = sqrtf(ss0), n1 = sqrtf(ss1);
        float inv0 = 1.f / (n0 + EPSF), inv1 = 1.f / (n1 + EPSF);
        float dotp = 0.f;
#pragma unroll
        for (int j = 0; j < 8; ++j) dotp += (h0v[j] * inv0) * (h1v[j] * inv1);
        dotp += __shfl_xor(dotp, 16); dotp += __shfl_xor(dotp, 32);
        dotp = fminf(fmaxf(dotp, -1.f + EPSF), 1.f - EPSF);
        float theta   = acosf(dotp);
        float scale   = 0.5f * (n0 + n1);
        float inv_sin = 1.f / sinf(theta);
        // theta >= acos(1-1e-6) ~ 1.4e-3 > EPS: slerp branch always taken
        float c0 = sinf((1.f - tval) * theta) * inv_sin * scale * inv0;
        float c1 = sinf(tval * theta) * inv_sin * scale * inv1;
#pragma unroll
        for (int j = 0; j < 8; ++j)
            hm[row][jb + j] = c0 * h0v[j] + c1 * h1v[j];
    }
    __syncthreads();

    // ---- decode layer 1 (all waves; kh pair duplicates per tile): g in A-frag layout
    bf16x8 afrag;
    {
        const int jb = kg * 8;
        float gv[8];
#pragma unroll
        for (int j = 0; j < 8; ++j) gv[j] = bd1[jb + j];
        for (int k = 0; k < 32; ++k) {
            float hk = hm[tile * 16 + m16][k];
#pragma unroll
            for (int j = 0; j < 8; ++j)
                gv[j] += hk * Wd1s[k * 33 + jb + j];
        }
#pragma unroll
        for (int j = 0; j < 8; ++j) afrag[j] = (bf16_t)gelu_f(gv[j]);
    }

    // ---- Phase 3: out_tile = g @ Wd2 + bd2. Wave (tile, kh): ntiles kh*64..kh*64+63.
    // Identical store pattern to the R0 kernel (scalar dword stores).
    for (int nt = kh * 64; nt < kh * 64 + 64; ++nt) {
        bf16x8 bfrag = Wd2p[nt * 64 + lane];
        f32x4 c = {0.f, 0.f, 0.f, 0.f};
        c = __builtin_amdgcn_mfma_f32_16x16x32_bf16(afrag, bfrag, c, 0, 0, 0);
        int ncol = nt * 16 + m16;
        float bias = bd2[ncol];
#pragma unroll
        for (int i = 0; i < 4; ++i)
            out[(size_t)(tileRow + kg * 4 + i) * DIM + ncol] = c[i] + bias;
    }
}

extern "C" void kernel_launch(void* const* d_in, const int* in_sizes, int n_in,
                              void* d_out, int out_size, void* d_ws, size_t ws_size,
                              hipStream_t stream) {
    const float* z0  = (const float*)d_in[0];
    const float* z1  = (const float*)d_in[1];
    const float* tp  = (const float*)d_in[2];
    const float* We1 = (const float*)d_in[3];
    const float* be1 = (const float*)d_in[4];
    const float* We2 = (const float*)d_in[5];
    const float* be2 = (const float*)d_in[6];
    const float* Wd1 = (const float*)d_in[7];
    const float* bd1 = (const float*)d_in[8];
    const float* Wd2 = (const float*)d_in[9];
    const float* bd2 = (const float*)d_in[10];
    float* out = (float*)d_out;

    bf16_t* We1p = (bf16_t*)d_ws;                         // 65536 bf16 = 128 KB
    bf16_t* Wd2p = (bf16_t*)((char*)d_ws + 65536 * 2);    // 65536 bf16 = 128 KB

    hipLaunchKernelGGL(pack_weights, dim3(64), dim3(256), 0, stream,
                       We1, Wd2, We1p, Wd2p);
    hipLaunchKernelGGL(fused_manifold, dim3(512), dim3(512), 0, stream,
                       z0, z1, tp, (const bf16x8*)We1p, be1, We2, be2,
                       Wd1, bd1, (const bf16x8*)Wd2p, bd2, out);
}

// Round 4
// 246.409 us; speedup vs baseline: 1.3999x; 1.3257x over previous
//
#include <hip/hip_runtime.h>
#include <hip/hip_bf16.h>

typedef __bf16 bf16_t;
typedef __attribute__((ext_vector_type(8))) __bf16 bf16x8;
typedef __attribute__((ext_vector_type(4))) float f32x4;

#define DIM 2048
#define LAT 32
#define EPSF 1e-6f

__device__ __forceinline__ float gelu_f(float x) {
    return 0.5f * x * (1.0f + erff(x * 0.7071067811865475f));
}

__device__ __forceinline__ void gl_lds16(const void* g, void* l) {
    __builtin_amdgcn_global_load_lds(
        (const __attribute__((address_space(1))) unsigned int*)g,
        (__attribute__((address_space(3))) unsigned int*)l, 16, 0, 0);
}

// Pack We1 (2048x32 f32) and Wd2 (32x2048 f32) into bf16 MFMA B-fragment layout.
// B-frag for mfma_f32_16x16x32_bf16: lane l needs B[k = kgrp*8 + i][n = ntile*16 + (l&15)],
// kgrp = l>>4, i = 0..7, stored contiguously (16B per lane).
__global__ void pack_weights(const float* __restrict__ We1,
                             const float* __restrict__ Wd2,
                             bf16_t* __restrict__ We1p,
                             bf16_t* __restrict__ Wd2p) {
    int tid = blockIdx.x * 256 + threadIdx.x;  // 0..16383
    if (tid < 8192) {
        int l  = tid & 63;
        int nt = (tid >> 6) & 1;
        int t  = tid >> 7;
        int kg = l >> 4, mm = l & 15;
        int k0 = t * 32 + kg * 8;
        int n  = nt * 16 + mm;
        bf16_t* dst = We1p + (size_t)tid * 8;
#pragma unroll
        for (int i = 0; i < 8; ++i)
            dst[i] = (bf16_t)We1[(size_t)(k0 + i) * LAT + n];
    } else {
        int id = tid - 8192;
        int l  = id & 63;
        int nt = id >> 6;
        int kg = l >> 4, mm = l & 15;
        int n  = nt * 16 + mm;
        bf16_t* dst = Wd2p + (size_t)id * 8;
#pragma unroll
        for (int i = 0; i < 8; ++i)
            dst[i] = (bf16_t)Wd2[(size_t)(kg * 8 + i) * DIM + n];
    }
}

// R0 geometry: 512 blocks x 256 threads (4 waves), each wave owns 16 rows
// end-to-end. K-loop reads (z0, z1, We1p) are staged into PER-WAVE LDS
// double-buffers via global_load_lds (16B), counted-vmcnt discipline,
// no barriers anywhere. LDS z layout is XOR-granule swizzled via the
// GLOBAL source address (rule #21: linear dest + pre-swizzled source).
//
// z staging granules (per tensor per K-step, 2KB = 2 insts of 1KB):
//   inst h, lane l -> row r = h*8 + (l>>3), col-quad q = (l&7) ^ (r&7)
//   LDS granule idx = h*64 + l; frag read lane(m16,kg) quad q at
//   offset (m16*8 + (q ^ (m16&7)))*16 -> uniform 8 lanes per bank group.
__global__ __launch_bounds__(256, 2)
void fused_manifold(const float* __restrict__ z0, const float* __restrict__ z1,
                    const float* __restrict__ tp,
                    const bf16x8* __restrict__ We1p,
                    const float* __restrict__ be1,
                    const float* __restrict__ We2,
                    const float* __restrict__ be2,
                    const float* __restrict__ Wd1,
                    const float* __restrict__ bd1,
                    const bf16x8* __restrict__ Wd2p,
                    const float* __restrict__ bd2,
                    float* __restrict__ out) {
    const int tid  = threadIdx.x;
    const int wave = tid >> 6;
    const int lane = tid & 63;
    const int m16  = lane & 15;
    const int kg   = lane >> 4;
    const int waveRow = blockIdx.x * 64 + wave * 16;

    __shared__ float We2s[LAT * 33];
    __shared__ float Wd1s[LAT * 33];
    __shared__ float s0[4][16][LAT + 1];   // also reused as hm after phase 2
    __shared__ float s1[4][16][LAT + 1];
    __shared__ __align__(16) char stage_raw[4][12288];  // per wave: z0[2][2K] z1[2][2K] w[2][2K]

    char* st = stage_raw[wave];
    char* zB0 = st;
    char* zB1 = st + 4096;
    char* wB  = st + 8192;

    for (int i = tid; i < LAT * LAT; i += 256) {
        int r = i >> 5, c = i & 31;
        We2s[r * 33 + c] = We2[i];
        Wd1s[r * 33 + c] = Wd1[i];
    }

    // ---- staging source pointers (pre-swizzled global addresses)
    const int r0 = lane >> 3;
    const int r1 = 8 + r0;
    const int q0 = (lane & 7) ^ (r0 & 7);
    const int q1 = (lane & 7) ^ (r1 & 7);
    const char* z0s0 = (const char*)(z0 + (size_t)(waveRow + r0) * DIM + q0 * 4);
    const char* z0s1 = (const char*)(z0 + (size_t)(waveRow + r1) * DIM + q1 * 4);
    const char* z1s0 = (const char*)(z1 + (size_t)(waveRow + r0) * DIM + q0 * 4);
    const char* z1s1 = (const char*)(z1 + (size_t)(waveRow + r1) * DIM + q1 * 4);
    const char* wsrc = (const char*)We1p + (size_t)lane * 16;

    // frag read offsets (lane-fixed)
    const int e   = m16 & 7;
    const int zlo = (m16 * 8 + ((2 * kg)     ^ e)) * 16;
    const int zhi = (m16 * 8 + ((2 * kg + 1) ^ e)) * 16;

#define STAGE(t, b) do {                                          \
        gl_lds16(z0s0 + (t) * 128,            zB0 + (b) * 2048);          \
        gl_lds16(z0s1 + (t) * 128,            zB0 + (b) * 2048 + 1024);   \
        gl_lds16(z1s0 + (t) * 128,            zB1 + (b) * 2048);          \
        gl_lds16(z1s1 + (t) * 128,            zB1 + (b) * 2048 + 1024);   \
        gl_lds16(wsrc + (size_t)(t) * 2048,        wB + (b) * 2048);          \
        gl_lds16(wsrc + (size_t)(t) * 2048 + 1024, wB + (b) * 2048 + 1024);   \
    } while (0)

    // ---- Phase 1: S = z_tile @ We1 (16 rows/wave, N=32, K=2048), both sources
    f32x4 acc00 = {0.f, 0.f, 0.f, 0.f};
    f32x4 acc01 = acc00, acc10 = acc00, acc11 = acc00;

    asm volatile("s_waitcnt vmcnt(0)" ::: "memory");  // clean vmcnt baseline
    STAGE(0, 0);
    STAGE(1, 1);

#pragma unroll 2
    for (int t = 0; t < 64; ++t) {
        const int b = t & 1;
        if (t < 63) { asm volatile("s_waitcnt vmcnt(6)" ::: "memory"); }
        else        { asm volatile("s_waitcnt vmcnt(0)" ::: "memory"); }
        const char* zb0 = zB0 + b * 2048;
        const char* zb1 = zB1 + b * 2048;
        const char* wb  = wB  + b * 2048;
        f32x4 a0lo = *(const f32x4*)(zb0 + zlo);
        f32x4 a0hi = *(const f32x4*)(zb0 + zhi);
        f32x4 a1lo = *(const f32x4*)(zb1 + zlo);
        f32x4 a1hi = *(const f32x4*)(zb1 + zhi);
        bf16x8 wf0 = *(const bf16x8*)(wb + lane * 16);
        bf16x8 wf1 = *(const bf16x8*)(wb + 1024 + lane * 16);
        bf16x8 a0, a1;
#pragma unroll
        for (int i = 0; i < 4; ++i) {
            a0[i]     = (bf16_t)a0lo[i];
            a0[i + 4] = (bf16_t)a0hi[i];
            a1[i]     = (bf16_t)a1lo[i];
            a1[i + 4] = (bf16_t)a1hi[i];
        }
        // frag LDS reads retired before restaging the same buffer
        asm volatile("s_waitcnt lgkmcnt(0)" ::: "memory");
        __builtin_amdgcn_sched_barrier(0);
        if (t < 62) STAGE(t + 2, b);
        acc00 = __builtin_amdgcn_mfma_f32_16x16x32_bf16(a0, wf0, acc00, 0, 0, 0);
        acc01 = __builtin_amdgcn_mfma_f32_16x16x32_bf16(a0, wf1, acc01, 0, 0, 0);
        acc10 = __builtin_amdgcn_mfma_f32_16x16x32_bf16(a1, wf0, acc10, 0, 0, 0);
        acc11 = __builtin_amdgcn_mfma_f32_16x16x32_bf16(a1, wf1, acc11, 0, 0, 0);
    }
#undef STAGE

    // bias + exact GELU, D-layout (col = m16 / 16+m16, rows kg*4+i) -> LDS rows.
    // All later phases are wave-local (per-wave LDS slices) -> no barriers.
    {
        float be1a = be1[m16], be1b = be1[16 + m16];
#pragma unroll
        for (int i = 0; i < 4; ++i) {
            int m = kg * 4 + i;
            s0[wave][m][m16]      = gelu_f(acc00[i] + be1a);
            s0[wave][m][16 + m16] = gelu_f(acc01[i] + be1b);
            s1[wave][m][m16]      = gelu_f(acc10[i] + be1a);
            s1[wave][m][16 + m16] = gelu_f(acc11[i] + be1b);
        }
    }

    // ---- Phase 2: per-lane row = m16, j-chunk = kg*8..kg*8+7 (fp32)
    const int jb = kg * 8;
    {
        const float tval = tp[0];
        float h0v[8], h1v[8];
#pragma unroll
        for (int j = 0; j < 8; ++j) { h0v[j] = be2[jb + j]; h1v[j] = h0v[j]; }
        for (int k = 0; k < 32; ++k) {
            float a0k = s0[wave][m16][k];
            float a1k = s1[wave][m16][k];
#pragma unroll
            for (int j = 0; j < 8; ++j) {
                float w = We2s[k * 33 + jb + j];
                h0v[j] += a0k * w;
                h1v[j] += a1k * w;
            }
        }
        float ss0 = 0.f, ss1 = 0.f;
#pragma unroll
        for (int j = 0; j < 8; ++j) { ss0 += h0v[j] * h0v[j]; ss1 += h1v[j] * h1v[j]; }
        ss0 += __shfl_xor(ss0, 16); ss0 += __shfl_xor(ss0, 32);
        ss1 += __shfl_xor(ss1, 16); ss1 += __shfl_xor(ss1, 32);
        float n0 = sqrtf(ss0), n1 = sqrtf(ss1);
        float inv0 = 1.f / (n0 + EPSF), inv1 = 1.f / (n1 + EPSF);
        float dotp = 0.f;
#pragma unroll
        for (int j = 0; j < 8; ++j) dotp += (h0v[j] * inv0) * (h1v[j] * inv1);
        dotp += __shfl_xor(dotp, 16); dotp += __shfl_xor(dotp, 32);
        dotp = fminf(fmaxf(dotp, -1.f + EPSF), 1.f - EPSF);
        float theta   = acosf(dotp);
        float scale   = 0.5f * (n0 + n1);
        float inv_sin = 1.f / sinf(theta);
        // theta >= acos(1-1e-6) ~ 1.4e-3 > EPS: slerp branch always taken
        float c0 = sinf((1.f - tval) * theta) * inv_sin * scale * inv0;
        float c1 = sinf(tval * theta) * inv_sin * scale * inv1;
        // hm overwrites s0[wave] (s0 fully consumed above; wave-lockstep safe)
#pragma unroll
        for (int j = 0; j < 8; ++j)
            s0[wave][m16][jb + j] = c0 * h0v[j] + c1 * h1v[j];
    }

    // ---- decode layer 1 (fp32): g lands exactly in A-fragment layout
    bf16x8 afrag;
    {
        float gv[8];
#pragma unroll
        for (int j = 0; j < 8; ++j) gv[j] = bd1[jb + j];
        for (int k = 0; k < 32; ++k) {
            float hk = s0[wave][m16][k];
#pragma unroll
            for (int j = 0; j < 8; ++j)
                gv[j] += hk * Wd1s[k * 33 + jb + j];
        }
#pragma unroll
        for (int j = 0; j < 8; ++j) afrag[j] = (bf16_t)gelu_f(gv[j]);
    }

    // ---- Phase 3: out_tile = g @ Wd2 + bd2  (16 rows/wave, N=2048, K=32)
    // Identical store pattern to R0 (scalar dword stores, WRITE-clean profile).
    for (int nt = 0; nt < 128; ++nt) {
        bf16x8 bfrag = Wd2p[nt * 64 + lane];
        f32x4 c = {0.f, 0.f, 0.f, 0.f};
        c = __builtin_amdgcn_mfma_f32_16x16x32_bf16(afrag, bfrag, c, 0, 0, 0);
        int ncol = nt * 16 + m16;
        float bias = bd2[ncol];
#pragma unroll
        for (int i = 0; i < 4; ++i)
            out[(size_t)(waveRow + kg * 4 + i) * DIM + ncol] = c[i] + bias;
    }
}

extern "C" void kernel_launch(void* const* d_in, const int* in_sizes, int n_in,
                              void* d_out, int out_size, void* d_ws, size_t ws_size,
                              hipStream_t stream) {
    const float* z0  = (const float*)d_in[0];
    const float* z1  = (const float*)d_in[1];
    const float* tp  = (const float*)d_in[2];
    const float* We1 = (const float*)d_in[3];
    const float* be1 = (const float*)d_in[4];
    const float* We2 = (const float*)d_in[5];
    const float* be2 = (const float*)d_in[6];
    const float* Wd1 = (const float*)d_in[7];
    const float* bd1 = (const float*)d_in[8];
    const float* Wd2 = (const float*)d_in[9];
    const float* bd2 = (const float*)d_in[10];
    float* out = (float*)d_out;

    bf16_t* We1p = (bf16_t*)d_ws;                         // 65536 bf16 = 128 KB
    bf16_t* Wd2p = (bf16_t*)((char*)d_ws + 65536 * 2);    // 65536 bf16 = 128 KB

    hipLaunchKernelGGL(pack_weights, dim3(64), dim3(256), 0, stream,
                       We1, Wd2, We1p, Wd2p);
    hipLaunchKernelGGL(fused_manifold, dim3(512), dim3(256), 0, stream,
                       z0, z1, tp, (const bf16x8*)We1p, be1, We2, be2,
                       Wd1, bd1, (const bf16x8*)Wd2p, bd2, out);
}

// Round 5
// 193.483 us; speedup vs baseline: 1.7828x; 1.2735x over previous
//
#include <hip/hip_runtime.h>
#include <hip/hip_bf16.h>

typedef __bf16 bf16_t;
typedef __attribute__((ext_vector_type(8))) __bf16 bf16x8;
typedef __attribute__((ext_vector_type(4))) float f32x4;

#define DIM 2048
#define LAT 32
#define EPSF 1e-6f

__device__ __forceinline__ float gelu_f(float x) {
    return 0.5f * x * (1.0f + erff(x * 0.7071067811865475f));
}

__device__ __forceinline__ void gl_lds16(const void* g, void* l) {
    __builtin_amdgcn_global_load_lds(
        (const __attribute__((address_space(1))) unsigned int*)g,
        (__attribute__((address_space(3))) unsigned int*)l, 16, 0, 0);
}

// Pack We1 (2048x32 f32) and Wd2 (32x2048 f32) into bf16 MFMA B-fragment layout
// for mfma_f32_16x16x32_bf16 (identical to R0 — verified).
__global__ void pack_weights(const float* __restrict__ We1,
                             const float* __restrict__ Wd2,
                             bf16_t* __restrict__ We1p,
                             bf16_t* __restrict__ Wd2p) {
    int tid = blockIdx.x * 256 + threadIdx.x;  // 0..16383
    if (tid < 8192) {
        int l  = tid & 63;
        int nt = (tid >> 6) & 1;
        int t  = tid >> 7;
        int kg = l >> 4, mm = l & 15;
        int k0 = t * 32 + kg * 8;
        int n  = nt * 16 + mm;
        bf16_t* dst = We1p + (size_t)tid * 8;
#pragma unroll
        for (int i = 0; i < 8; ++i)
            dst[i] = (bf16_t)We1[(size_t)(k0 + i) * LAT + n];
    } else {
        int id = tid - 8192;
        int l  = id & 63;
        int nt = id >> 6;
        int kg = l >> 4, mm = l & 15;
        int n  = nt * 16 + mm;
        bf16_t* dst = Wd2p + (size_t)id * 8;
#pragma unroll
        for (int i = 0; i < 8; ++i)
            dst[i] = (bf16_t)Wd2[(size_t)(kg * 8 + i) * DIM + n];
    }
}

// 512 blocks x 256 threads (4 waves), wave owns 16 rows end-to-end (R0 geometry,
// the only traffic-clean shape). NEW: all large-volume memory instructions are
// CONTIGUOUS per instruction:
//  - phase 1: z staged via global_load_lds, 1 instr = one row-pair (2 x 512B
//    contiguous); tensor-alternating counted-vmcnt pipeline, no barriers.
//  - phase 3: MFMA -> LDS slab -> 512B-contiguous dwordx4 row stores.
__global__ __launch_bounds__(256, 2)
void fused_manifold(const float* __restrict__ z0, const float* __restrict__ z1,
                    const float* __restrict__ tp,
                    const bf16x8* __restrict__ We1p,
                    const float* __restrict__ be1,
                    const float* __restrict__ We2,
                    const float* __restrict__ be2,
                    const float* __restrict__ We2_unused,
                    const float* __restrict__ Wd1,
                    const float* __restrict__ bd1,
                    const bf16x8* __restrict__ Wd2p,
                    const float* __restrict__ bd2,
                    float* __restrict__ out) {
    const int tid  = threadIdx.x;
    const int wave = tid >> 6;
    const int lane = tid & 63;
    const int m16  = lane & 15;
    const int kg   = lane >> 4;
    const int blockRow = blockIdx.x * 64;
    const int waveRow  = blockRow + wave * 16;

    // LDS map (total 81152 B -> 2 blocks/CU):
    //  [0, 66560)       stage: wave slice 16640 = z0: 8 pairs x 1040, z1: +8320
    //                   (reused after phase 2 as the phase-3 out slab, pitch 528)
    //  [66560, 75008)   S bf16 [2][64][33] (src0/src1 gelu tiles; src0 reused as hm)
    //  [75008, 79104)   We2s f32 [32][32]
    //  [79104, 81152)   Wd1s bf16 [32][32]
    __shared__ __align__(16) unsigned char lds[81152];
    bf16_t* S  = (bf16_t*)(lds + 66560);
    float*  W2 = (float*) (lds + 75008);
    bf16_t* W1 = (bf16_t*)(lds + 79104);
    char*   stw = (char*)lds + wave * 16640;

    for (int i = tid; i < LAT * LAT; i += 256) {
        W2[i] = We2[i];
        W1[i] = (bf16_t)Wd1[i];
    }
    const float tval = tp[0];
    __syncthreads();   // W2/W1 visible to all waves; drains nothing (no VMEM out)

    // ---- Phase 1: S = z_tile @ We1 (16 rows/wave, N=32, K=2048), both sources.
    // Staging: per superstep ss (BK=128 floats = 512 B/row): 8 gl_lds instrs per
    // tensor; instr i: lanes 0-31 -> row 2i bytes [ss*512, +512), lanes 32-63 ->
    // row 2i+1. Dest linear at pair base (pitch 1040 => A-frag ds_read_b128 is
    // bank-uniform: start bank = 4*((pair + 2*kg + j) % 8), 8 lanes each).
    const char* z0src = (const char*)z0 + (size_t)(waveRow + (lane >> 5)) * (DIM * 4) + (lane & 31) * 16;
    const char* z1src = (const char*)z1 + (size_t)(waveRow + (lane >> 5)) * (DIM * 4) + (lane & 31) * 16;

#define STG(srcp, dstoff, ssv)                                             \
    {                                                                      \
        _Pragma("unroll")                                                  \
        for (int i_ = 0; i_ < 8; ++i_)                                     \
            gl_lds16(srcp + (size_t)i_ * 16384 + (ssv) * 512,              \
                     stw + (dstoff) + i_ * 1040);                          \
    }

    f32x4 acc00 = {0.f, 0.f, 0.f, 0.f};
    f32x4 acc01 = acc00, acc10 = acc00, acc11 = acc00;
    const char* abase0 = stw + (m16 >> 1) * 1040 + (m16 & 1) * 512 + kg * 32;
    const char* abase1 = abase0 + 8320;

    STG(z0src, 0, 0);                                   // vmcnt: 8 outstanding

#pragma unroll 1
    for (int ss = 0; ss < 16; ++ss) {
        // B-fragments for this superstep (same K-range serves z0 and z1 chains).
        // Loaded BEFORE z1-staging so compiler waits for their use never drain it.
        bf16x8 Bf0[4], Bf1[4];
#pragma unroll
        for (int k = 0; k < 4; ++k) {
            int gk = ss * 4 + k;
            Bf0[k] = We1p[(gk * 2 + 0) * 64 + lane];
            Bf1[k] = We1p[(gk * 2 + 1) * 64 + lane];
        }
        __builtin_amdgcn_sched_barrier(0);
        STG(z1src, 8320, ss);                           // outstanding: 8 z0 + 8 B + 8 z1
        asm volatile("s_waitcnt vmcnt(16)" ::: "memory");  // z0(ss) LDS ready
#pragma unroll
        for (int k = 0; k < 4; ++k) {
            f32x4 lo = *(const f32x4*)(abase0 + k * 128);
            f32x4 hi = *(const f32x4*)(abase0 + k * 128 + 16);
            bf16x8 a;
#pragma unroll
            for (int i = 0; i < 4; ++i) { a[i] = (bf16_t)lo[i]; a[i + 4] = (bf16_t)hi[i]; }
            acc00 = __builtin_amdgcn_mfma_f32_16x16x32_bf16(a, Bf0[k], acc00, 0, 0, 0);
            acc01 = __builtin_amdgcn_mfma_f32_16x16x32_bf16(a, Bf1[k], acc01, 0, 0, 0);
        }
        asm volatile("s_waitcnt lgkmcnt(0)" ::: "memory");   // z0 buffer reads retired
        __builtin_amdgcn_sched_barrier(0);
        if (ss < 15) {
            STG(z0src, 0, ss + 1);
            asm volatile("s_waitcnt vmcnt(8)" ::: "memory"); // z1(ss) ready
        } else {
            asm volatile("s_waitcnt vmcnt(0)" ::: "memory");
        }
#pragma unroll
        for (int k = 0; k < 4; ++k) {
            f32x4 lo = *(const f32x4*)(abase1 + k * 128);
            f32x4 hi = *(const f32x4*)(abase1 + k * 128 + 16);
            bf16x8 a;
#pragma unroll
            for (int i = 0; i < 4; ++i) { a[i] = (bf16_t)lo[i]; a[i + 4] = (bf16_t)hi[i]; }
            acc10 = __builtin_amdgcn_mfma_f32_16x16x32_bf16(a, Bf0[k], acc10, 0, 0, 0);
            acc11 = __builtin_amdgcn_mfma_f32_16x16x32_bf16(a, Bf1[k], acc11, 0, 0, 0);
        }
        asm volatile("s_waitcnt lgkmcnt(0)" ::: "memory");   // z1 buffer reads retired
        __builtin_amdgcn_sched_barrier(0);
    }
#undef STG

    // ---- bias + exact GELU -> S tiles (bf16), D-layout col=m16, rows kg*4+i.
    {
        float be1a = be1[m16], be1b = be1[16 + m16];
#pragma unroll
        for (int i = 0; i < 4; ++i) {
            int row = wave * 16 + kg * 4 + i;
            S[row * 33 + m16]               = (bf16_t)gelu_f(acc00[i] + be1a);
            S[row * 33 + 16 + m16]          = (bf16_t)gelu_f(acc01[i] + be1b);
            S[2112 + row * 33 + m16]        = (bf16_t)gelu_f(acc10[i] + be1a);
            S[2112 + row * 33 + 16 + m16]   = (bf16_t)gelu_f(acc11[i] + be1b);
        }
    }

    // ---- Phase 2 (wave-local): encode-2 + slerp; row = m16, j-chunk = kg*8..+7
    const int jb = kg * 8;
    {
        const int row = wave * 16 + m16;
        float h0v[8], h1v[8];
#pragma unroll
        for (int j = 0; j < 8; ++j) { h0v[j] = be2[jb + j]; h1v[j] = h0v[j]; }
        for (int k = 0; k < 32; ++k) {
            float a0k = (float)S[row * 33 + k];
            float a1k = (float)S[2112 + row * 33 + k];
#pragma unroll
            for (int j = 0; j < 8; ++j) {
                float w = W2[k * 32 + jb + j];
                h0v[j] += a0k * w;
                h1v[j] += a1k * w;
            }
        }
        float ss0 = 0.f, ss1 = 0.f;
#pragma unroll
        for (int j = 0; j < 8; ++j) { ss0 += h0v[j] * h0v[j]; ss1 += h1v[j] * h1v[j]; }
        ss0 += __shfl_xor(ss0, 16); ss0 += __shfl_xor(ss0, 32);
        ss1 += __shfl_xor(ss1, 16); ss1 += __shfl_xor(ss1, 32);
        float n0 = sqrtf(ss0), n1 = sqrtf(ss1);
        float inv0 = 1.f / (n0 + EPSF), inv1 = 1.f / (n1 + EPSF);
        float dotp = 0.f;
#pragma unroll
        for (int j = 0; j < 8; ++j) dotp += (h0v[j] * inv0) * (h1v[j] * inv1);
        dotp += __shfl_xor(dotp, 16); dotp += __shfl_xor(dotp, 32);
        dotp = fminf(fmaxf(dotp, -1.f + EPSF), 1.f - EPSF);
        float theta   = acosf(dotp);
        float scale   = 0.5f * (n0 + n1);
        float inv_sin = 1.f / sinf(theta);
        // theta >= acos(1-1e-6) ~ 1.4e-3 > EPS: slerp branch always taken
        float c0 = sinf((1.f - tval) * theta) * inv_sin * scale * inv0;
        float c1 = sinf(tval * theta) * inv_sin * scale * inv1;
        // hm overwrites S src0 slice (fully consumed above; wave-lockstep safe)
#pragma unroll
        for (int j = 0; j < 8; ++j)
            S[row * 33 + jb + j] = (bf16_t)(c0 * h0v[j] + c1 * h1v[j]);
    }

    // ---- decode layer 1 (wave-local): g lands exactly in A-fragment layout
    bf16x8 afrag;
    {
        const int row = wave * 16 + m16;
        float gv[8];
#pragma unroll
        for (int j = 0; j < 8; ++j) gv[j] = bd1[jb + j];
        for (int k = 0; k < 32; ++k) {
            float hk = (float)S[row * 33 + k];
#pragma unroll
            for (int j = 0; j < 8; ++j)
                gv[j] += hk * (float)W1[k * 32 + jb + j];
        }
#pragma unroll
        for (int j = 0; j < 8; ++j) afrag[j] = (bf16_t)gelu_f(gv[j]);
    }

    // All waves done with the stage region before it becomes the out slab.
    __syncthreads();

    // ---- Phase 3: out = g @ Wd2 + bd2, via swapped-operand MFMA (R1-verified
    // D-layout: row=m16, cols=nt*16+kg*4+i) -> LDS slab (pitch 528, bank-uniform)
    // -> CONTIGUOUS 512B-per-row dwordx4 stores.
    {
        const int q    = lane & 31;
        const int rsel = lane >> 5;
        for (int c = 0; c < 16; ++c) {
#pragma unroll
            for (int j = 0; j < 8; ++j) {
                int nt = c * 8 + j;
                bf16x8 bfrag = Wd2p[nt * 64 + lane];
                f32x4 d = {0.f, 0.f, 0.f, 0.f};
                d = __builtin_amdgcn_mfma_f32_16x16x32_bf16(bfrag, afrag, d, 0, 0, 0);
                *(f32x4*)((char*)lds + (size_t)(wave * 16 + m16) * 528 + j * 64 + kg * 16) = d;
            }
            f32x4 bv = *(const f32x4*)(bd2 + c * 128 + q * 4);
#pragma unroll
            for (int r = 0; r < 8; ++r) {
                int row2 = r * 2 + rsel;
                f32x4 v = *(const f32x4*)((char*)lds + (size_t)(wave * 16 + row2) * 528 + q * 16);
                f32x4 o;
#pragma unroll
                for (int i = 0; i < 4; ++i) o[i] = v[i] + bv[i];
                *(f32x4*)(out + (size_t)(blockRow + wave * 16 + row2) * DIM + c * 128 + q * 4) = o;
            }
        }
    }
}

extern "C" void kernel_launch(void* const* d_in, const int* in_sizes, int n_in,
                              void* d_out, int out_size, void* d_ws, size_t ws_size,
                              hipStream_t stream) {
    const float* z0  = (const float*)d_in[0];
    const float* z1  = (const float*)d_in[1];
    const float* tp  = (const float*)d_in[2];
    const float* We1 = (const float*)d_in[3];
    const float* be1 = (const float*)d_in[4];
    const float* We2 = (const float*)d_in[5];
    const float* be2 = (const float*)d_in[6];
    const float* Wd1 = (const float*)d_in[7];
    const float* bd1 = (const float*)d_in[8];
    const float* Wd2 = (const float*)d_in[9];
    const float* bd2 = (const float*)d_in[10];
    float* out = (float*)d_out;

    bf16_t* We1p = (bf16_t*)d_ws;                         // 65536 bf16 = 128 KB
    bf16_t* Wd2p = (bf16_t*)((char*)d_ws + 65536 * 2);    // 65536 bf16 = 128 KB

    hipLaunchKernelGGL(pack_weights, dim3(64), dim3(256), 0, stream,
                       We1, Wd2, We1p, Wd2p);
    hipLaunchKernelGGL(fused_manifold, dim3(512), dim3(256), 0, stream,
                       z0, z1, tp, (const bf16x8*)We1p, be1, We2, be2,
                       We2, Wd1, bd1, (const bf16x8*)Wd2p, bd2, out);
}

// Round 6
// 177.525 us; speedup vs baseline: 1.9431x; 1.0899x over previous
//
#include <hip/hip_runtime.h>
#include <hip/hip_bf16.h>

typedef __bf16 bf16_t;
typedef __attribute__((ext_vector_type(8))) __bf16 bf16x8;
typedef __attribute__((ext_vector_type(4))) float f32x4;

#define DIM 2048
#define LAT 32
#define EPSF 1e-6f

__device__ __forceinline__ float gelu_f(float x) {
    return 0.5f * x * (1.0f + erff(x * 0.7071067811865475f));
}

__device__ __forceinline__ void gl_lds16(const void* g, void* l) {
    __builtin_amdgcn_global_load_lds(
        (const __attribute__((address_space(1))) unsigned int*)g,
        (__attribute__((address_space(3))) unsigned int*)l, 16, 0, 0);
}

// Pack We1 (2048x32 f32) and Wd2 (32x2048 f32) into bf16 MFMA B-fragment layout
// for mfma_f32_16x16x32_bf16 (identical to R0 — verified).
__global__ void pack_weights(const float* __restrict__ We1,
                             const float* __restrict__ Wd2,
                             bf16_t* __restrict__ We1p,
                             bf16_t* __restrict__ Wd2p) {
    int tid = blockIdx.x * 256 + threadIdx.x;  // 0..16383
    if (tid < 8192) {
        int l  = tid & 63;
        int nt = (tid >> 6) & 1;
        int t  = tid >> 7;
        int kg = l >> 4, mm = l & 15;
        int k0 = t * 32 + kg * 8;
        int n  = nt * 16 + mm;
        bf16_t* dst = We1p + (size_t)tid * 8;
#pragma unroll
        for (int i = 0; i < 8; ++i)
            dst[i] = (bf16_t)We1[(size_t)(k0 + i) * LAT + n];
    } else {
        int id = tid - 8192;
        int l  = id & 63;
        int nt = id >> 6;
        int kg = l >> 4, mm = l & 15;
        int n  = nt * 16 + mm;
        bf16_t* dst = Wd2p + (size_t)id * 8;
#pragma unroll
        for (int i = 0; i < 8; ++i)
            dst[i] = (bf16_t)Wd2[(size_t)(kg * 8 + i) * DIM + n];
    }
}

// R4 structure + NEW: per-(block,wave) cyclic PHASE ROTATION phi of the K-sweep
// (phase 1) and the column sweep (phase 3). Same bytes, same cyclic order,
// same single coherent front per row — but instantaneous addresses across the
// machine are spread over 16 different 512B phases (channel de-clumping).
__global__ __launch_bounds__(256, 2)
void fused_manifold(const float* __restrict__ z0, const float* __restrict__ z1,
                    const float* __restrict__ tp,
                    const bf16x8* __restrict__ We1p,
                    const float* __restrict__ be1,
                    const float* __restrict__ We2,
                    const float* __restrict__ be2,
                    const float* __restrict__ We2_unused,
                    const float* __restrict__ Wd1,
                    const float* __restrict__ bd1,
                    const bf16x8* __restrict__ Wd2p,
                    const float* __restrict__ bd2,
                    float* __restrict__ out) {
    const int tid  = threadIdx.x;
    const int wave = tid >> 6;
    const int lane = tid & 63;
    const int m16  = lane & 15;
    const int kg   = lane >> 4;
    const int blockRow = blockIdx.x * 64;
    const int waveRow  = blockRow + wave * 16;
    const int phi  = ((int)blockIdx.x * 5 + wave * 4) & 15;

    // LDS map (total 81152 B -> 2 blocks/CU):
    //  [0, 66560)       stage: wave slice 16640 = z0: 8 pairs x 1040, z1: +8320
    //                   (reused after phase 2 as the phase-3 out slab, pitch 528)
    //  [66560, 75008)   S bf16 [2][64][33] (src0/src1 gelu tiles; src0 reused as hm)
    //  [75008, 79104)   We2s f32 [32][32]
    //  [79104, 81152)   Wd1s bf16 [32][32]
    __shared__ __align__(16) unsigned char lds[81152];
    bf16_t* S  = (bf16_t*)(lds + 66560);
    float*  W2 = (float*) (lds + 75008);
    bf16_t* W1 = (bf16_t*)(lds + 79104);
    char*   stw = (char*)lds + wave * 16640;

    for (int i = tid; i < LAT * LAT; i += 256) {
        W2[i] = We2[i];
        W1[i] = (bf16_t)Wd1[i];
    }
    const float tval = tp[0];
    __syncthreads();   // W2/W1 visible to all waves

    // ---- Phase 1: S = z_tile @ We1 (16 rows/wave, N=32, K=2048), both sources.
    // Superstep = BK=128 floats = 512 B/row; K-block index kb = (ss + phi) & 15.
    const char* z0src = (const char*)z0 + (size_t)(waveRow + (lane >> 5)) * (DIM * 4) + (lane & 31) * 16;
    const char* z1src = (const char*)z1 + (size_t)(waveRow + (lane >> 5)) * (DIM * 4) + (lane & 31) * 16;

#define STG(srcp, dstoff, kbv)                                             \
    {                                                                      \
        _Pragma("unroll")                                                  \
        for (int i_ = 0; i_ < 8; ++i_)                                     \
            gl_lds16(srcp + (size_t)i_ * 16384 + (kbv) * 512,              \
                     stw + (dstoff) + i_ * 1040);                          \
    }

    f32x4 acc00 = {0.f, 0.f, 0.f, 0.f};
    f32x4 acc01 = acc00, acc10 = acc00, acc11 = acc00;
    const char* abase0 = stw + (m16 >> 1) * 1040 + (m16 & 1) * 512 + kg * 32;
    const char* abase1 = abase0 + 8320;

    STG(z0src, 0, phi);                                 // vmcnt: 8 outstanding

#pragma unroll 1
    for (int ss = 0; ss < 16; ++ss) {
        const int kb  = (ss + phi) & 15;
        const int kbn = (ss + 1 + phi) & 15;
        // B-fragments for this K-block (same K-range serves z0 and z1 chains).
        bf16x8 Bf0[4], Bf1[4];
#pragma unroll
        for (int k = 0; k < 4; ++k) {
            int gk = kb * 4 + k;
            Bf0[k] = We1p[(gk * 2 + 0) * 64 + lane];
            Bf1[k] = We1p[(gk * 2 + 1) * 64 + lane];
        }
        __builtin_amdgcn_sched_barrier(0);
        STG(z1src, 8320, kb);                           // outstanding: 8 z0 + 8 B + 8 z1
        asm volatile("s_waitcnt vmcnt(16)" ::: "memory");  // z0(kb) LDS ready
#pragma unroll
        for (int k = 0; k < 4; ++k) {
            f32x4 lo = *(const f32x4*)(abase0 + k * 128);
            f32x4 hi = *(const f32x4*)(abase0 + k * 128 + 16);
            bf16x8 a;
#pragma unroll
            for (int i = 0; i < 4; ++i) { a[i] = (bf16_t)lo[i]; a[i + 4] = (bf16_t)hi[i]; }
            acc00 = __builtin_amdgcn_mfma_f32_16x16x32_bf16(a, Bf0[k], acc00, 0, 0, 0);
            acc01 = __builtin_amdgcn_mfma_f32_16x16x32_bf16(a, Bf1[k], acc01, 0, 0, 0);
        }
        asm volatile("s_waitcnt lgkmcnt(0)" ::: "memory");   // z0 buffer reads retired
        __builtin_amdgcn_sched_barrier(0);
        if (ss < 15) {
            STG(z0src, 0, kbn);
            asm volatile("s_waitcnt vmcnt(8)" ::: "memory"); // z1(kb) ready
        } else {
            asm volatile("s_waitcnt vmcnt(0)" ::: "memory");
        }
#pragma unroll
        for (int k = 0; k < 4; ++k) {
            f32x4 lo = *(const f32x4*)(abase1 + k * 128);
            f32x4 hi = *(const f32x4*)(abase1 + k * 128 + 16);
            bf16x8 a;
#pragma unroll
            for (int i = 0; i < 4; ++i) { a[i] = (bf16_t)lo[i]; a[i + 4] = (bf16_t)hi[i]; }
            acc10 = __builtin_amdgcn_mfma_f32_16x16x32_bf16(a, Bf0[k], acc10, 0, 0, 0);
            acc11 = __builtin_amdgcn_mfma_f32_16x16x32_bf16(a, Bf1[k], acc11, 0, 0, 0);
        }
        asm volatile("s_waitcnt lgkmcnt(0)" ::: "memory");   // z1 buffer reads retired
        __builtin_amdgcn_sched_barrier(0);
    }
#undef STG

    // ---- bias + exact GELU -> S tiles (bf16), D-layout col=m16, rows kg*4+i.
    {
        float be1a = be1[m16], be1b = be1[16 + m16];
#pragma unroll
        for (int i = 0; i < 4; ++i) {
            int row = wave * 16 + kg * 4 + i;
            S[row * 33 + m16]               = (bf16_t)gelu_f(acc00[i] + be1a);
            S[row * 33 + 16 + m16]          = (bf16_t)gelu_f(acc01[i] + be1b);
            S[2112 + row * 33 + m16]        = (bf16_t)gelu_f(acc10[i] + be1a);
            S[2112 + row * 33 + 16 + m16]   = (bf16_t)gelu_f(acc11[i] + be1b);
        }
    }

    // ---- Phase 2 (wave-local): encode-2 + slerp; row = m16, j-chunk = kg*8..+7
    const int jb = kg * 8;
    {
        const int row = wave * 16 + m16;
        float h0v[8], h1v[8];
#pragma unroll
        for (int j = 0; j < 8; ++j) { h0v[j] = be2[jb + j]; h1v[j] = h0v[j]; }
        for (int k = 0; k < 32; ++k) {
            float a0k = (float)S[row * 33 + k];
            float a1k = (float)S[2112 + row * 33 + k];
#pragma unroll
            for (int j = 0; j < 8; ++j) {
                float w = W2[k * 32 + jb + j];
                h0v[j] += a0k * w;
                h1v[j] += a1k * w;
            }
        }
        float ss0 = 0.f, ss1 = 0.f;
#pragma unroll
        for (int j = 0; j < 8; ++j) { ss0 += h0v[j] * h0v[j]; ss1 += h1v[j] * h1v[j]; }
        ss0 += __shfl_xor(ss0, 16); ss0 += __shfl_xor(ss0, 32);
        ss1 += __shfl_xor(ss1, 16); ss1 += __shfl_xor(ss1, 32);
        float n0 = sqrtf(ss0), n1 = sqrtf(ss1);
        float inv0 = 1.f / (n0 + EPSF), inv1 = 1.f / (n1 + EPSF);
        float dotp = 0.f;
#pragma unroll
        for (int j = 0; j < 8; ++j) dotp += (h0v[j] * inv0) * (h1v[j] * inv1);
        dotp += __shfl_xor(dotp, 16); dotp += __shfl_xor(dotp, 32);
        dotp = fminf(fmaxf(dotp, -1.f + EPSF), 1.f - EPSF);
        float theta   = acosf(dotp);
        float scale   = 0.5f * (n0 + n1);
        float inv_sin = 1.f / sinf(theta);
        // theta >= acos(1-1e-6) ~ 1.4e-3 > EPS: slerp branch always taken
        float c0 = sinf((1.f - tval) * theta) * inv_sin * scale * inv0;
        float c1 = sinf(tval * theta) * inv_sin * scale * inv1;
        // hm overwrites S src0 slice (fully consumed above; wave-lockstep safe)
#pragma unroll
        for (int j = 0; j < 8; ++j)
            S[row * 33 + jb + j] = (bf16_t)(c0 * h0v[j] + c1 * h1v[j]);
    }

    // ---- decode layer 1 (wave-local): g lands exactly in A-fragment layout
    bf16x8 afrag;
    {
        const int row = wave * 16 + m16;
        float gv[8];
#pragma unroll
        for (int j = 0; j < 8; ++j) gv[j] = bd1[jb + j];
        for (int k = 0; k < 32; ++k) {
            float hk = (float)S[row * 33 + k];
#pragma unroll
            for (int j = 0; j < 8; ++j)
                gv[j] += hk * (float)W1[k * 32 + jb + j];
        }
#pragma unroll
        for (int j = 0; j < 8; ++j) afrag[j] = (bf16_t)gelu_f(gv[j]);
    }

    // All waves done with the stage region before it becomes the out slab.
    __syncthreads();

    // ---- Phase 3: out = g @ Wd2 + bd2, via swapped-operand MFMA (R1-verified
    // D-layout: row=m16, cols=nt*16+kg*4+i) -> LDS slab (pitch 528) ->
    // CONTIGUOUS 512B-per-row dwordx4 stores. Column sweep rotated by phi.
    {
        const int q    = lane & 31;
        const int rsel = lane >> 5;
        for (int ci = 0; ci < 16; ++ci) {
            const int c = (ci + phi) & 15;
#pragma unroll
            for (int j = 0; j < 8; ++j) {
                int nt = c * 8 + j;
                bf16x8 bfrag = Wd2p[nt * 64 + lane];
                f32x4 d = {0.f, 0.f, 0.f, 0.f};
                d = __builtin_amdgcn_mfma_f32_16x16x32_bf16(bfrag, afrag, d, 0, 0, 0);
                *(f32x4*)((char*)lds + (size_t)(wave * 16 + m16) * 528 + j * 64 + kg * 16) = d;
            }
            f32x4 bv = *(const f32x4*)(bd2 + c * 128 + q * 4);
#pragma unroll
            for (int r = 0; r < 8; ++r) {
                int row2 = r * 2 + rsel;
                f32x4 v = *(const f32x4*)((char*)lds + (size_t)(wave * 16 + row2) * 528 + q * 16);
                f32x4 o;
#pragma unroll
                for (int i = 0; i < 4; ++i) o[i] = v[i] + bv[i];
                *(f32x4*)(out + (size_t)(blockRow + wave * 16 + row2) * DIM + c * 128 + q * 4) = o;
            }
        }
    }
}

extern "C" void kernel_launch(void* const* d_in, const int* in_sizes, int n_in,
                              void* d_out, int out_size, void* d_ws, size_t ws_size,
                              hipStream_t stream) {
    const float* z0  = (const float*)d_in[0];
    const float* z1  = (const float*)d_in[1];
    const float* tp  = (const float*)d_in[2];
    const float* We1 = (const float*)d_in[3];
    const float* be1 = (const float*)d_in[4];
    const float* We2 = (const float*)d_in[5];
    const float* be2 = (const float*)d_in[6];
    const float* Wd1 = (const float*)d_in[7];
    const float* bd1 = (const float*)d_in[8];
    const float* Wd2 = (const float*)d_in[9];
    const float* bd2 = (const float*)d_in[10];
    float* out = (float*)d_out;

    bf16_t* We1p = (bf16_t*)d_ws;                         // 65536 bf16 = 128 KB
    bf16_t* Wd2p = (bf16_t*)((char*)d_ws + 65536 * 2);    // 65536 bf16 = 128 KB

    hipLaunchKernelGGL(pack_weights, dim3(64), dim3(256), 0, stream,
                       We1, Wd2, We1p, Wd2p);
    hipLaunchKernelGGL(fused_manifold, dim3(512), dim3(256), 0, stream,
                       z0, z1, tp, (const bf16x8*)We1p, be1, We2, be2,
                       We2, Wd1, bd1, (const bf16x8*)Wd2p, bd2, out);
}